// Round 7
// baseline (523.903 us; speedup 1.0000x reference)
//
#include <hip/hip_runtime.h>
#include <hip/hip_bf16.h>
#include <math.h>

#define NEGINF (-INFINITY)

typedef float f32x4 __attribute__((ext_vector_type(4)));

__device__ __forceinline__ float wave_max_f(float m) {
#pragma unroll
  for (int d = 32; d > 0; d >>= 1) m = fmaxf(m, __shfl_xor(m, d, 64));
  return m;
}
__device__ __forceinline__ float wave_sum_f(float s) {
#pragma unroll
  for (int d = 32; d > 0; d >>= 1) s += __shfl_xor(s, d, 64);
  return s;
}
__device__ __forceinline__ int wave_sum_i(int s) {
#pragma unroll
  for (int d = 32; d > 0; d >>= 1) s += __shfl_xor(s, d, 64);
  return s;
}

// Whole-wave shift-right-by-1 via DPP (pure VALU). Lane l gets lane l-1's
// value; lane 0 gets 0 (caller overrides).
__device__ __forceinline__ float dpp_wave_shr1(float x) {
  int r = __builtin_amdgcn_mov_dpp(__float_as_int(x), 0x138, 0xf, 0xf, true);
  return __int_as_float(r);
}

// ---------------------------------------------------------------------------
// Kernel A: per (b,t) row of ctc_out[V]: logsumexp, then gather into packed
// row layout (stride ROWF=LANES*4+8 floats = 960 B):
//   row[0 .. LANES*4)  = label lps, quad s -> labels jbase(s)..+3 (clamped)
//   row[LANES*4]       = blank lp
// ---------------------------------------------------------------------------
__global__ __launch_bounds__(256) void kA_lse_gather(
    const float* __restrict__ ctc_out, const int* __restrict__ ctc_label,
    float* __restrict__ lp, int B, int T, int V, int L, int LANES,
    int TPAD, int ROWF)
{
  extern __shared__ float shrow[];  // V floats
  __shared__ float wred[4];
  int row = blockIdx.x;             // b*T + t
  int b = row / T;
  int t = row - b * T;
  int tid = threadIdx.x;
  int w = tid >> 6;
  const float* x = ctc_out + (size_t)row * V;

  float m = NEGINF;
  int nf4 = V >> 2;
  for (int k = tid; k < nf4; k += 256) {
    float4 v = reinterpret_cast<const float4*>(x)[k];
    reinterpret_cast<float4*>(shrow)[k] = v;
    m = fmaxf(m, fmaxf(fmaxf(v.x, v.y), fmaxf(v.z, v.w)));
  }
  for (int k = (nf4 << 2) + tid; k < V; k += 256) {
    float v = x[k]; shrow[k] = v; m = fmaxf(m, v);
  }
  m = wave_max_f(m);
  if ((tid & 63) == 0) wred[w] = m;
  __syncthreads();
  float bm = fmaxf(fmaxf(wred[0], wred[1]), fmaxf(wred[2], wred[3]));
  __syncthreads();

  float s = 0.f;
  for (int k = tid; k < V; k += 256) s += __expf(shrow[k] - bm);
  s = wave_sum_f(s);
  if ((tid & 63) == 0) wred[w] = s;
  __syncthreads();
  float lse = bm + __logf(wred[0] + wred[1] + wred[2] + wred[3]);

  const int* lab = ctc_label + (size_t)b * L;
  float* dst = lp + ((size_t)b * TPAD + t) * ROWF;
  int nq = LANES * 4;
  for (int idx = tid; idx < nq; idx += 256) {
    int sl = idx >> 2, q = idx & 3;
    int jb = ((7 * sl) >> 1) + 1;
    int j = jb + q; if (j > L) j = L;
    int vi = lab[j - 1];
    if ((unsigned)vi >= (unsigned)V) vi = 0;
    dst[idx] = shrow[vi] - lse;
  }
  if (tid == 0) dst[nq] = shrow[0] - lse;
}

// ---------------------------------------------------------------------------
// Kernel B: Viterbi forced alignment, one wave per batch item.
// Lane l owns states 7l..7l+6. lp staged global->LDS via global_load_lds in
// 16-row double-buffered segments. 8-deep LDS register ring (slots A..H).
// Waits ONLY at bodies 0 and 8 of each segment (lgkmcnt(0); body 8 also
// vmcnt(0)) - on CDNA, global_load_lds bumps lgkmcnt too, and s_waitcnt is a
// TOTAL-count gate, so frequent small-N lgkm waits stall on in-flight DMA.
// With waits 8 bodies apart, everything they cover is >600cy old -> free.
// offrow ((T-1) x 128B) lives in LDS; backtrace = batched speculative reads.
// ---------------------------------------------------------------------------
__global__ __launch_bounds__(64, 1) void kB_viterbi(
    const float* __restrict__ lp, const int* __restrict__ ctc_label,
    float* __restrict__ ali, int B, int T, int L, int TPAD, int ROWF)
{
  extern __shared__ float smemf[];
  // LDS layout: buf0 @0 (15360B), buf1 @15360, offrow @30720 ((T-1)*128B)
  const int N = 2 * L + 1;
  const int LANES = (N + 6) / 7;
  const unsigned STGB = (unsigned)(16 * ROWF * 4);     // 15360
  const unsigned OFFROW = 2u * STGB;                   // 30720

  int b = blockIdx.x;
  int lane = threadIdx.x;
  const float* lpb = lp + (size_t)b * TPAD * ROWF;
  const int* lab = ctc_label + (size_t)b * L;
  int qlane = (lane < LANES) ? lane : (LANES - 1);
  int blkoff = LANES * 4;            // blank float-offset within row
  unsigned sbase = __builtin_amdgcn_groupstaticsize();

  int i0 = lane * 7;
  float a0v, a1v, a2v, a3v, a4v, a5v, a6v;
  int twv[7];
  int tlo[7];
  unsigned rng[7];
#pragma unroll
  for (int s = 0; s < 7; ++s) {
    int i = i0 + s;
    bool valid = (i < N);
    bool odd = (i & 1) != 0;
    int li = (i - 1) >> 1;
    int myl = (odd && valid) ? lab[li] : 0;
    int pl  = (odd && valid && i >= 3) ? lab[li - 1] : -1;
    twv[s] = ((!odd) || (i == 1) || (myl == pl)) ? 1 : 0;
    if (valid) {
      tlo[s] = (i + 1) >> 1;                 // t >= ceil(i/2)
      int thi = T - L + (i >> 1);            // t <= T-L+floor(i/2)
      rng[s] = (unsigned)(thi - tlo[s]);
    } else {
      tlo[s] = T + 2;
      rng[s] = 0u;
    }
  }

  // t=0 init (direct global reads, before any asm LDS traffic).
  {
    f32x4 q00 = reinterpret_cast<const f32x4*>(lpb)[qlane];
    float bl00 = lpb[blkoff];
    a0v = (i0 == 0) ? bl00 : NEGINF;
    a1v = NEGINF; a2v = NEGINF; a3v = NEGINF; a4v = NEGINF; a5v = NEGINF;
    a6v = NEGINF;
    if (i0 + 1 == 1) a1v = q00.x;   // only lane 0 state 1
  }

  // DMA one 16-row segment starting at global row row0 into buffer bufidx.
  int ndma = ROWF >> 4;              // 15 ops of 1KB
#define DMA_SEG(row0, bufidx)                                                 \
  {                                                                           \
    const float* gsrc_ = lpb + (size_t)(row0) * ROWF;                         \
    char* dbase_ = (char*)smemf + (unsigned)(bufidx) * STGB;                  \
    for (int kk_ = 0; kk_ < ndma; ++kk_) {                                    \
      __builtin_amdgcn_global_load_lds(                                       \
          (const unsigned int*)(gsrc_ + (size_t)kk_ * 256 + lane * 4),        \
          (unsigned int*)(dbase_ + kk_ * 1024), 16, 0, 0);                    \
    }                                                                         \
    __builtin_amdgcn_sched_barrier(0);                                        \
  }

  f32x4 rqA, rqB, rqC, rqD, rqE, rqF, rqG, rqH;
  float rblA, rblB, rblC, rblD, rblE, rblF, rblG, rblH;

#define RINGRD(SL, qaddr, baddr)                                              \
  asm volatile("ds_read_b128 %0, %1" : "=v"(rq##SL) : "v"(qaddr));            \
  asm volatile("ds_read_b32 %0, %1" : "=v"(rbl##SL) : "v"(baddr));

#define STEP(s, P0, P1, P2, OCS, ND, OD)                                      \
  {                                                                           \
    bool c01 = (P0) > (P1);                                                   \
    float m01 = c01 ? (P0) : (P1);                                            \
    bool take3 = (twv[s] == 0) && !(m01 > (P2));                              \
    float asel = take3 ? (P2) : m01;                                          \
    OD = take3 ? 2u : (c01 ? 0u : 1u);                                        \
    float lps = (((lane + (s)) & 1) ? (OCS) : blc);                           \
    ND = asel + lps;                                                          \
    bool feas = (unsigned)(tt - tlo[s]) <= rng[s];                            \
    ND = feas ? ND : NEGINF;                                                  \
  }

  // One DP body. SL = ring slot letter, UL = compile-time row-in-segment.
  // Waits only at UL==0 (lgkm) and UL==8 (vm+lgkm). DMA for next segment
  // issued at UL==0 right after its wait.
#define BODY(SL, UL)                                                          \
  {                                                                           \
    const int tt = tt0 + (UL);                                                \
    if ((UL) == 0) {                                                          \
      asm volatile("s_waitcnt lgkmcnt(0)");                                   \
      __builtin_amdgcn_sched_barrier(0);                                      \
      if (sg + 1 < NSEG) { DMA_SEG(tt0 + 16, ((sg + 1) & 1)) }                \
    }                                                                         \
    if ((UL) == 8) {                                                          \
      asm volatile("s_waitcnt vmcnt(0) lgkmcnt(0)");                          \
      __builtin_amdgcn_sched_barrier(0);                                      \
    }                                                                         \
    float blc = rbl##SL;                                                      \
    f32x4 oc = rq##SL;                                                        \
    float n0, n1, n2, n3, n4, n5, n6;                                         \
    unsigned o0, o1, o2, o3, o4, o5, o6;                                      \
    STEP(5, a5v, a4v, a3v, oc.z, n5, o5)                                      \
    STEP(6, a6v, a5v, a4v, oc.w, n6, o6)                                      \
    float t6n = dpp_wave_shr1(n6);                                            \
    float t5n = dpp_wave_shr1(n5);                                            \
    STEP(0, a0v, t6, t5, oc.x, n0, o0)                                        \
    STEP(1, a1v, a0v, t6, oc.x, n1, o1)                                       \
    STEP(2, a2v, a1v, a0v, oc.y, n2, o2)                                      \
    STEP(3, a3v, a2v, a1v, oc.y, n3, o3)                                      \
    STEP(4, a4v, a3v, a2v, oc.z, n4, o4)                                      \
    unsigned pack = o0 | (o1 << 2) | (o2 << 4) | (o3 << 6) | (o4 << 8) |      \
                    (o5 << 10) | (o6 << 12);                                  \
    asm volatile("ds_write_b16 %0, %1" :: "v"(wa), "v"(pack));                \
    wa += 128;                                                                \
    {                                                                         \
      unsigned qa = ((UL) < 8) ? (qcur + ((UL) + 8) * 960u)                   \
                               : (qnxt + ((UL) - 8) * 960u);                  \
      unsigned ba = ((UL) < 8) ? (bcur + ((UL) + 8) * 960u)                   \
                               : (bnxt + ((UL) - 8) * 960u);                  \
      RINGRD(SL, qa, ba)                                                      \
    }                                                                         \
    a0v = n0; a1v = n1; a2v = n2; a3v = n3; a4v = n4; a5v = n5; a6v = n6;     \
    t6 = (lane == 0) ? NEGINF : t6n;                                          \
    t5 = (lane == 0) ? NEGINF : t5n;                                          \
  }

  // Tail body: per-body full waits (rare; last segment only).
#define TBODY(SL, UL)                                                         \
  {                                                                           \
    const int tt = tt0 + (UL);                                                \
    asm volatile("s_waitcnt vmcnt(0) lgkmcnt(0)");                            \
    __builtin_amdgcn_sched_barrier(0);                                        \
    float blc = rbl##SL;                                                      \
    f32x4 oc = rq##SL;                                                        \
    float n0, n1, n2, n3, n4, n5, n6;                                         \
    unsigned o0, o1, o2, o3, o4, o5, o6;                                      \
    STEP(5, a5v, a4v, a3v, oc.z, n5, o5)                                      \
    STEP(6, a6v, a5v, a4v, oc.w, n6, o6)                                      \
    float t6n = dpp_wave_shr1(n6);                                            \
    float t5n = dpp_wave_shr1(n5);                                            \
    STEP(0, a0v, t6, t5, oc.x, n0, o0)                                        \
    STEP(1, a1v, a0v, t6, oc.x, n1, o1)                                       \
    STEP(2, a2v, a1v, a0v, oc.y, n2, o2)                                      \
    STEP(3, a3v, a2v, a1v, oc.y, n3, o3)                                      \
    STEP(4, a4v, a3v, a2v, oc.z, n4, o4)                                      \
    unsigned pack = o0 | (o1 << 2) | (o2 << 4) | (o3 << 6) | (o4 << 8) |      \
                    (o5 << 10) | (o6 << 12);                                  \
    asm volatile("ds_write_b16 %0, %1" :: "v"(wa), "v"(pack));                \
    wa += 128;                                                                \
    {                                                                         \
      unsigned qa = ((UL) < 8) ? (qcur + ((UL) + 8) * 960u)                   \
                               : (qnxt + ((UL) - 8) * 960u);                  \
      unsigned ba = ((UL) < 8) ? (bcur + ((UL) + 8) * 960u)                   \
                               : (bnxt + ((UL) - 8) * 960u);                  \
      RINGRD(SL, qa, ba)                                                      \
    }                                                                         \
    a0v = n0; a1v = n1; a2v = n2; a3v = n3; a4v = n4; a5v = n5; a6v = n6;     \
    t6 = (lane == 0) ? NEGINF : t6n;                                          \
    t5 = (lane == 0) ? NEGINF : t5n;                                          \
  }

  // Prologue: DMA segment 0 (rows 1..16) into buf0, drain, prime 8 slots.
  DMA_SEG(1, 0)
  asm volatile("s_waitcnt vmcnt(0) lgkmcnt(0)");
  __builtin_amdgcn_sched_barrier(0);

  unsigned wa = sbase + OFFROW + (unsigned)(lane * 2);
  {
    unsigned q0 = sbase + (unsigned)(qlane * 16);
    unsigned b0 = sbase + (unsigned)(blkoff * 4);
    RINGRD(A, q0 + 0u * 960u, b0 + 0u * 960u)
    RINGRD(B, q0 + 1u * 960u, b0 + 1u * 960u)
    RINGRD(C, q0 + 2u * 960u, b0 + 2u * 960u)
    RINGRD(D, q0 + 3u * 960u, b0 + 3u * 960u)
    RINGRD(E, q0 + 4u * 960u, b0 + 4u * 960u)
    RINGRD(F, q0 + 5u * 960u, b0 + 5u * 960u)
    RINGRD(G, q0 + 6u * 960u, b0 + 6u * 960u)
    RINGRD(H, q0 + 7u * 960u, b0 + 7u * 960u)
  }

  // Initial shifted values from t=0 state (outside hot loop).
  float t6 = __shfl_up(a6v, 1, 64);
  float t5 = __shfl_up(a5v, 1, 64);
  if (lane == 0) { t6 = NEGINF; t5 = NEGINF; }

  int NSEG = (T - 1 + 15) >> 4;
  for (int sg = 0; sg < NSEG; ++sg) {
    int tt0 = 1 + 16 * sg;
    unsigned bufc = sbase + (unsigned)(sg & 1) * STGB;
    unsigned bufn = sbase + (unsigned)((sg + 1) & 1) * STGB;
    unsigned qcur = bufc + (unsigned)(qlane * 16);
    unsigned qnxt = bufn + (unsigned)(qlane * 16);
    unsigned bcur = bufc + (unsigned)(blkoff * 4);
    unsigned bnxt = bufn + (unsigned)(blkoff * 4);
    int rem = T - tt0;   // bodies this segment (>=16 except last)
    if (rem >= 16) {
      BODY(A, 0)  BODY(B, 1)  BODY(C, 2)  BODY(D, 3)
      BODY(E, 4)  BODY(F, 5)  BODY(G, 6)  BODY(H, 7)
      BODY(A, 8)  BODY(B, 9)  BODY(C, 10) BODY(D, 11)
      BODY(E, 12) BODY(F, 13) BODY(G, 14) BODY(H, 15)
    } else {
      if (0 < rem)  { TBODY(A, 0) }
      if (1 < rem)  { TBODY(B, 1) }
      if (2 < rem)  { TBODY(C, 2) }
      if (3 < rem)  { TBODY(D, 3) }
      if (4 < rem)  { TBODY(E, 4) }
      if (5 < rem)  { TBODY(F, 5) }
      if (6 < rem)  { TBODY(G, 6) }
      if (7 < rem)  { TBODY(H, 7) }
      if (8 < rem)  { TBODY(A, 8) }
      if (9 < rem)  { TBODY(B, 9) }
      if (10 < rem) { TBODY(C, 10) }
      if (11 < rem) { TBODY(D, 11) }
      if (12 < rem) { TBODY(E, 12) }
      if (13 < rem) { TBODY(F, 13) }
      if (14 < rem) { TBODY(G, 14) }
      if (15 < rem) { TBODY(H, 15) }
    }
  }
#undef TBODY
#undef BODY
#undef STEP
#undef RINGRD
#undef DMA_SEG

  // Drain everything before compiler-visible LDS reads (backtrace).
  asm volatile("s_waitcnt vmcnt(0) lgkmcnt(0)" ::: "memory");
  __builtin_amdgcn_sched_barrier(0);

  // Final-state values (state i -> lane i/7, slot i%7).
  int iN1 = N - 1, iN2 = N - 2;
  auto pick = [&](int sIdx) {
    float r = a0v;
    r = (sIdx == 1) ? a1v : r;
    r = (sIdx == 2) ? a2v : r;
    r = (sIdx == 3) ? a3v : r;
    r = (sIdx == 4) ? a4v : r;
    r = (sIdx == 5) ? a5v : r;
    r = (sIdx == 6) ? a6v : r;
    return r;
  };
  float vlast = __shfl(pick(iN1 % 7), iN1 / 7, 64);
  float vprev = __shfl(pick(iN2 % 7), iN2 / 7, 64);
  bool use_last = vlast > vprev;
  int pre = use_last ? iN1 : iN2;

  float al[4] = {0.f, 0.f, 0.f, 0.f};
  {
    int lbl = L - 1; int rr = lbl >> 6, ln = lbl & 63;
#pragma unroll
    for (int r = 0; r < 4; ++r)
      if (!use_last && rr == r && lane == ln) al[r] = (float)T;
  }

  // Backtrace from LDS offrow (rows of 64 u16; entry g of row t-1).
  const unsigned short* offrow =
      (const unsigned short*)((char*)smemf + OFFROW);
  int t = T - 1;
  int g = pre / 7, mm = pre - g * 7;
  while (t >= 1) {
    int K = (t < 7) ? t : 7;
    int pcur = g * 7 + mm;
    int gmax = g;
    unsigned short w0v = offrow[(size_t)(t - 1) * 64 + g];
    unsigned short cw[7][3];
    int gmn[7];
#pragma unroll
    for (int j = 1; j < 7; ++j) {
      if (j < K) {
        int lo = pcur - 2 * j; if (lo < 0) lo = 0;
        int gm = lo / 7;
        gmn[j] = gm;
#pragma unroll
        for (int r = 0; r < 3; ++r) {
          int gg = gm + r; if (gg > gmax) gg = gmax;
          cw[j][r] = offrow[(size_t)(t - 1 - j) * 64 + gg];
        }
      }
    }
#pragma unroll
    for (int j = 0; j < 7; ++j) {
      if (j < K) {
        unsigned w;
        if (j == 0) {
          w = w0v;
        } else {
          int gi = g - gmn[j];
          unsigned wva = cw[j][0], wvb = cw[j][1], wvc = cw[j][2];
          w = (gi == 0) ? wva : ((gi == 1) ? wvb : wvc);
        }
        unsigned off = (w >> (2 * mm)) & 3u;
        mm -= (int)off;
        bool bor = mm < 0;
        g = bor ? (g - 1) : g;
        mm = bor ? (mm + 7) : mm;
        int cur = g * 7 + mm;
        if (cur & 1) {
          int lbl = cur >> 1;
          int rr = lbl >> 6, ln = lbl & 63;
#pragma unroll
          for (int r = 0; r < 4; ++r)
            if (rr == r && lane == ln) al[r] = (float)(t - j);
        }
      }
    }
    t -= K;
  }

#pragma unroll
  for (int r = 0; r < 4; ++r) {
    int l = lane + 64 * r;
    if (l < L) ali[(size_t)b * L + l] = al[r];
  }
}

// ---------------------------------------------------------------------------
// Kernel C: one wave per (b,layer,o<L) row: dot(ali_out_row, pos) - ali,
// masked, squared; 4 rows/block -> per-block partial sum.
// ---------------------------------------------------------------------------
__global__ __launch_bounds__(256) void kC_rows(
    const float* __restrict__ ali_out, const float* __restrict__ ali,
    const int* __restrict__ ali_beg, float* __restrict__ partials,
    int B, int layers, int L, int T)
{
  __shared__ float ps[4];
  int wid = threadIdx.x >> 6, lane = threadIdx.x & 63;
  int row = blockIdx.x * 4 + wid;
  int nrows = B * layers * L;
  float val = 0.f;
  if (row < nrows) {
    int o = row % L;
    int bl = row / L;
    int layer = bl % layers;
    int b = bl / layers;
    const float* x = ali_out + ((size_t)(b * layers + layer) * (L + 1) + o) * T;
    float s = 0.f;
    if ((T & 3) == 0) {
      int nf4 = T >> 2;
      for (int k = lane; k < nf4; k += 64) {
        float4 v = reinterpret_cast<const float4*>(x)[k];
        float base = (float)(4 * k);
        s += v.x * (base + 1.f) + v.y * (base + 2.f) +
             v.z * (base + 3.f) + v.w * (base + 4.f);
      }
    } else {
      for (int k = lane; k < T; k += 64) s += x[k] * (float)(k + 1);
    }
    s = wave_sum_f(s);
    int cnt = 0;
    for (int l = lane; l < L; l += 64)
      cnt += (ali_beg[(size_t)b * L + l] != -1) ? 1 : 0;
    cnt = wave_sum_i(cnt);
    if (lane == 0) {
      float lat = (o >= cnt) ? 0.f : (s - ali[(size_t)b * L + o]);
      val = lat * lat;
    }
  }
  if (lane == 0) ps[wid] = val;
  __syncthreads();
  if (threadIdx.x == 0) partials[blockIdx.x] = ps[0] + ps[1] + ps[2] + ps[3];
}

// ---------------------------------------------------------------------------
// Kernel D: reduce partials, compute total = layers * sum(ylen), write scalar.
// ---------------------------------------------------------------------------
__global__ __launch_bounds__(256) void kD_final(
    const float* __restrict__ partials, int nparts,
    const int* __restrict__ ali_beg, int BL, int layers, int T,
    float* __restrict__ out)
{
  __shared__ float wred[4];
  __shared__ int wcnt[4];
  int tid = threadIdx.x, w = tid >> 6;
  float s = 0.f;
  for (int k = tid; k < nparts; k += 256) s += partials[k];
  s = wave_sum_f(s);
  int c = 0;
  for (int k = tid; k < BL; k += 256) c += (ali_beg[k] != -1) ? 1 : 0;
  c = wave_sum_i(c);
  if ((tid & 63) == 0) { wred[w] = s; wcnt[w] = c; }
  __syncthreads();
  if (tid == 0) {
    float ss = wred[0] + wred[1] + wred[2] + wred[3];
    float total = (float)(wcnt[0] + wcnt[1] + wcnt[2] + wcnt[3]) * (float)layers;
    out[0] = ss / total / (float)T;
  }
}

extern "C" void kernel_launch(void* const* d_in, const int* in_sizes, int n_in,
                              void* d_out, int out_size, void* d_ws, size_t ws_size,
                              hipStream_t stream)
{
  const float* ali_out   = (const float*)d_in[0];
  const int*   ali_beg   = (const int*)d_in[1];
  // d_in[2] ali_end, d_in[3] enc_mask, d_in[6] ctc_len: unused by reference math
  const float* ctc_out   = (const float*)d_in[4];
  const int*   ctc_label = (const int*)d_in[5];

  int B = in_sizes[6];
  int L = in_sizes[1] / B;
  int T = in_sizes[3] / B;
  int V = (int)((long long)in_sizes[4] / ((long long)B * T));
  int layers = (int)((long long)in_sizes[0] / ((long long)B * (L + 1) * T));

  int N = 2 * L + 1;
  int LANES = (N + 6) / 7;           // 58
  int ROWF = LANES * 4 + 8;          // 240 floats (960 B)
  int TPAD = T + 64;                 // DMA over-read pad

  // workspace layout
  float* lp = (float*)d_ws;                              // B*TPAD*ROWF floats
  float* ali = lp + (size_t)B * TPAD * ROWF;             // B*L
  float* partials = ali + (size_t)B * L;                 // gridC
  int nrows = B * layers * L;
  int gridC = (nrows + 3) / 4;

  // A: logsumexp + gather into packed rows
  size_t shA = (size_t)V * sizeof(float);
  hipLaunchKernelGGL(kA_lse_gather, dim3(B * T), dim3(256), shA, stream,
                     ctc_out, ctc_label, lp, B, T, V, L, LANES, TPAD, ROWF);

  // B: Viterbi forward + backtrace (one wave per batch item)
  // LDS: 2 staging buffers (2*16*ROWF*4 B) + offrow ((T-1)*128 B)
  size_t shB = (size_t)2 * 16 * ROWF * sizeof(float) + (size_t)(T - 1) * 128;
  hipFuncSetAttribute(reinterpret_cast<const void*>(kB_viterbi),
                      hipFuncAttributeMaxDynamicSharedMemorySize, (int)shB);
  hipLaunchKernelGGL(kB_viterbi, dim3(B), dim3(64), shB, stream,
                     lp, ctc_label, ali, B, T, L, TPAD, ROWF);

  // C: expected-position rows + squared residual partials
  hipLaunchKernelGGL(kC_rows, dim3(gridC), dim3(256), 0, stream,
                     ali_out, ali, ali_beg, partials, B, layers, L, T);

  // D: finalize scalar
  hipLaunchKernelGGL(kD_final, dim3(1), dim3(256), 0, stream,
                     partials, gridC, ali_beg, B * L, layers, T, (float*)d_out);
}

// Round 8
// 462.670 us; speedup vs baseline: 1.1323x; 1.1323x over previous
//
#include <hip/hip_runtime.h>
#include <hip/hip_bf16.h>
#include <math.h>

#define NEGINF (-INFINITY)

typedef float f32x4 __attribute__((ext_vector_type(4)));

__device__ __forceinline__ float wave_max_f(float m) {
#pragma unroll
  for (int d = 32; d > 0; d >>= 1) m = fmaxf(m, __shfl_xor(m, d, 64));
  return m;
}
__device__ __forceinline__ float wave_sum_f(float s) {
#pragma unroll
  for (int d = 32; d > 0; d >>= 1) s += __shfl_xor(s, d, 64);
  return s;
}
__device__ __forceinline__ int wave_sum_i(int s) {
#pragma unroll
  for (int d = 32; d > 0; d >>= 1) s += __shfl_xor(s, d, 64);
  return s;
}

// Whole-wave shift-right-by-1 via DPP (pure VALU). Lane l gets lane l-1's
// value; lane 0 gets 0 (caller overrides).
__device__ __forceinline__ float dpp_wave_shr1(float x) {
  int r = __builtin_amdgcn_mov_dpp(__float_as_int(x), 0x138, 0xf, 0xf, true);
  return __int_as_float(r);
}

// ---------------------------------------------------------------------------
// Kernel A: per (b,t) row of ctc_out[V]: logsumexp, then gather into packed
// row layout (stride ROWF=LANES*4+8 floats = 960 B):
//   row[0 .. LANES*4)  = label lps, quad s -> labels jbase(s)..+3 (clamped)
//   row[LANES*4]       = blank lp   (i.e. lane 58's quad .x = blank)
//   row[LANES*4+1 ..]  = zero pad
// ---------------------------------------------------------------------------
__global__ __launch_bounds__(256) void kA_lse_gather(
    const float* __restrict__ ctc_out, const int* __restrict__ ctc_label,
    float* __restrict__ lp, int B, int T, int V, int L, int LANES,
    int TPAD, int ROWF)
{
  extern __shared__ float shrow[];  // V floats
  __shared__ float wred[4];
  int row = blockIdx.x;             // b*T + t
  int b = row / T;
  int t = row - b * T;
  int tid = threadIdx.x;
  int w = tid >> 6;
  const float* x = ctc_out + (size_t)row * V;

  float m = NEGINF;
  int nf4 = V >> 2;
  for (int k = tid; k < nf4; k += 256) {
    float4 v = reinterpret_cast<const float4*>(x)[k];
    reinterpret_cast<float4*>(shrow)[k] = v;
    m = fmaxf(m, fmaxf(fmaxf(v.x, v.y), fmaxf(v.z, v.w)));
  }
  for (int k = (nf4 << 2) + tid; k < V; k += 256) {
    float v = x[k]; shrow[k] = v; m = fmaxf(m, v);
  }
  m = wave_max_f(m);
  if ((tid & 63) == 0) wred[w] = m;
  __syncthreads();
  float bm = fmaxf(fmaxf(wred[0], wred[1]), fmaxf(wred[2], wred[3]));
  __syncthreads();

  float s = 0.f;
  for (int k = tid; k < V; k += 256) s += __expf(shrow[k] - bm);
  s = wave_sum_f(s);
  if ((tid & 63) == 0) wred[w] = s;
  __syncthreads();
  float lse = bm + __logf(wred[0] + wred[1] + wred[2] + wred[3]);

  const int* lab = ctc_label + (size_t)b * L;
  float* dst = lp + ((size_t)b * TPAD + t) * ROWF;
  int nq = LANES * 4;
  for (int idx = tid; idx < nq; idx += 256) {
    int sl = idx >> 2, q = idx & 3;
    int jb = ((7 * sl) >> 1) + 1;
    int j = jb + q; if (j > L) j = L;
    int vi = lab[j - 1];
    if ((unsigned)vi >= (unsigned)V) vi = 0;
    dst[idx] = shrow[vi] - lse;
  }
  if (tid == 0) dst[nq] = shrow[0] - lse;
  for (int z = nq + 1 + tid; z < ROWF; z += 256) dst[z] = 0.f;  // pad
}

// ---------------------------------------------------------------------------
// Kernel B: Viterbi forced alignment, one wave per batch item.
// Lane l owns states 7l..7l+6. NO LDS staging, NO global_load_lds: per body
// exactly ONE asm global_load_dwordx4 into an 8-slot pinned register ring
// (plain global loads pipeline from a single wave). Blank lp comes free via
// readlane(slot.x, 58) since lane 58's quad starts at the blank offset.
// The only in-loop wait: s_waitcnt vmcnt(7) (oldest slot done). Transition
// offsets (2b/state) packed per lane into u16, written to LDS offrow
// ((T-1) x 128B) fire-and-forget; backtrace = batched speculative LDS reads.
// ---------------------------------------------------------------------------
__global__ __launch_bounds__(64, 1) void kB_viterbi(
    const float* __restrict__ lp, const int* __restrict__ ctc_label,
    float* __restrict__ ali, int B, int T, int L, int TPAD, int ROWF)
{
  extern __shared__ float smemf[];   // offrow only: (T-1)*128 B
  const int N = 2 * L + 1;
  const int LANES = (N + 6) / 7;     // 58

  int b = blockIdx.x;
  int lane = threadIdx.x;
  const float* lpb = lp + (size_t)b * TPAD * ROWF;
  const int* lab = ctc_label + (size_t)b * L;
  int qlane = (lane < LANES) ? lane : LANES;  // lanes 58..63 -> 58 (blank quad)
  if (qlane > LANES) qlane = LANES;
  int blkoff = LANES * 4;            // blank float-offset within row (232)

  int i0 = lane * 7;
  float a0v, a1v, a2v, a3v, a4v, a5v, a6v;
  int twv[7];
  int tlo[7];
  unsigned rng[7];
#pragma unroll
  for (int s = 0; s < 7; ++s) {
    int i = i0 + s;
    bool valid = (i < N);
    bool odd = (i & 1) != 0;
    int li = (i - 1) >> 1;
    int myl = (odd && valid) ? lab[li] : 0;
    int pl  = (odd && valid && i >= 3) ? lab[li - 1] : -1;
    twv[s] = ((!odd) || (i == 1) || (myl == pl)) ? 1 : 0;
    if (valid) {
      tlo[s] = (i + 1) >> 1;                 // t >= ceil(i/2)
      int thi = T - L + (i >> 1);            // t <= T-L+floor(i/2)
      rng[s] = (unsigned)(thi - tlo[s]);
    } else {
      tlo[s] = T + 2;
      rng[s] = 0u;
    }
  }

  // t=0 init (plain compiler loads; drained before the asm ring starts).
  {
    f32x4 q00 = *reinterpret_cast<const f32x4*>(lpb + qlane * 4);
    float bl00 = lpb[blkoff];
    a0v = (i0 == 0) ? bl00 : NEGINF;
    a1v = NEGINF; a2v = NEGINF; a3v = NEGINF; a4v = NEGINF; a5v = NEGINF;
    a6v = NEGINF;
    if (i0 + 1 == 1) a1v = q00.x;   // only lane 0 state 1
  }

  f32x4 rq0, rq1, rq2, rq3, rq4, rq5, rq6, rq7;
  unsigned short* offrow_w = (unsigned short*)smemf;

  // Ensure no compiler vmem is outstanding before our counted ring starts.
  asm volatile("s_waitcnt vmcnt(0) lgkmcnt(0)");
  __builtin_amdgcn_sched_barrier(0);

  unsigned long long base64 = (unsigned long long)lpb;
  unsigned voff = (unsigned)(qlane * 16) + 960u;   // row 1

#define LOADQ(SL)                                                             \
  asm volatile("global_load_dwordx4 %0, %1, %2"                               \
               : "=v"(rq##SL) : "v"(voff), "s"(base64));                      \
  voff += 960u;

  // Prologue: rows 1..8 -> slots 1..7,0 (slot = row & 7). voff ends at row 9.
  LOADQ(1) LOADQ(2) LOADQ(3) LOADQ(4) LOADQ(5) LOADQ(6) LOADQ(7) LOADQ(0)

#define STEP_F(s, P0, P1, P2, OCS, ND, OD)                                    \
  {                                                                           \
    bool c01 = (P0) > (P1);                                                   \
    float m01 = c01 ? (P0) : (P1);                                            \
    bool take3 = (twv[s] == 0) && !(m01 > (P2));                              \
    float asel = take3 ? (P2) : m01;                                          \
    OD = take3 ? 2u : (c01 ? 0u : 1u);                                        \
    float lps = (((lane + (s)) & 1) ? (OCS) : blc);                           \
    ND = asel + lps;                                                          \
  }

#define STEP_S(s, P0, P1, P2, OCS, ND, OD)                                    \
  {                                                                           \
    STEP_F(s, P0, P1, P2, OCS, ND, OD)                                        \
    bool feas = (unsigned)(tt - tlo[s]) <= rng[s];                            \
    ND = feas ? ND : NEGINF;                                                  \
  }

  // One DP body. SL = ring slot (== tt&7 since tt0 === 1 mod 8), K = body
  // index in group. STEPs consume rq##SL, then the same slot is re-issued
  // for row tt+8 (register dataflow orders read-before-rewrite).
#define BODYC(SL, K, STEPM)                                                   \
  {                                                                           \
    const int tt = tt0 + (K);                                                 \
    asm volatile("s_waitcnt vmcnt(7)");                                       \
    __builtin_amdgcn_sched_barrier(0);                                        \
    float blc = __int_as_float(                                               \
        __builtin_amdgcn_readlane(__float_as_int(rq##SL.x), 58));             \
    float n0, n1, n2, n3, n4, n5, n6;                                         \
    unsigned o0, o1, o2, o3, o4, o5, o6;                                      \
    STEPM(5, a5v, a4v, a3v, rq##SL.z, n5, o5)                                 \
    STEPM(6, a6v, a5v, a4v, rq##SL.w, n6, o6)                                 \
    float t6n = dpp_wave_shr1(n6);                                            \
    float t5n = dpp_wave_shr1(n5);                                            \
    STEPM(0, a0v, t6, t5, rq##SL.x, n0, o0)                                   \
    STEPM(1, a1v, a0v, t6, rq##SL.x, n1, o1)                                  \
    STEPM(2, a2v, a1v, a0v, rq##SL.y, n2, o2)                                 \
    STEPM(3, a3v, a2v, a1v, rq##SL.y, n3, o3)                                 \
    STEPM(4, a4v, a3v, a2v, rq##SL.z, n4, o4)                                 \
    unsigned pack = o0 | (o1 << 2) | (o2 << 4) | (o3 << 6) | (o4 << 8) |      \
                    (o5 << 10) | (o6 << 12);                                  \
    offrow_w[(size_t)(tt - 1) * 64 + lane] = (unsigned short)pack;            \
    LOADQ(SL)                                                                 \
    a0v = n0; a1v = n1; a2v = n2; a3v = n3; a4v = n4; a5v = n5; a6v = n6;     \
    t6 = (lane == 0) ? NEGINF : t6n;                                          \
    t5 = (lane == 0) ? NEGINF : t5n;                                          \
  }

  // Initial shifted values from t=0 state (outside hot loop).
  float t6 = __shfl_up(a6v, 1, 64);
  float t5 = __shfl_up(a5v, 1, 64);
  if (lane == 0) { t6 = NEGINF; t5 = NEGINF; }

  int tt0 = 1;
  for (; tt0 + 8 <= T; tt0 += 8) {
    if (tt0 >= L && tt0 + 7 <= T - L) {
      BODYC(1, 0, STEP_F) BODYC(2, 1, STEP_F) BODYC(3, 2, STEP_F)
      BODYC(4, 3, STEP_F) BODYC(5, 4, STEP_F) BODYC(6, 5, STEP_F)
      BODYC(7, 6, STEP_F) BODYC(0, 7, STEP_F)
    } else {
      BODYC(1, 0, STEP_S) BODYC(2, 1, STEP_S) BODYC(3, 2, STEP_S)
      BODYC(4, 3, STEP_S) BODYC(5, 4, STEP_S) BODYC(6, 5, STEP_S)
      BODYC(7, 6, STEP_S) BODYC(0, 7, STEP_S)
    }
  }
  {
    int rem = T - tt0;   // 0..7 remaining bodies
    if (rem > 0) { BODYC(1, 0, STEP_S) }
    if (rem > 1) { BODYC(2, 1, STEP_S) }
    if (rem > 2) { BODYC(3, 2, STEP_S) }
    if (rem > 3) { BODYC(4, 3, STEP_S) }
    if (rem > 4) { BODYC(5, 4, STEP_S) }
    if (rem > 5) { BODYC(6, 5, STEP_S) }
    if (rem > 6) { BODYC(7, 6, STEP_S) }
  }
#undef BODYC
#undef STEP_S
#undef STEP_F
#undef LOADQ

  // Drain the ring; keep destinations live until after the drain.
  asm volatile("s_waitcnt vmcnt(0) lgkmcnt(0)" ::: "memory");
  __builtin_amdgcn_sched_barrier(0);
  asm volatile("" :: "v"(rq0), "v"(rq1), "v"(rq2), "v"(rq3));
  asm volatile("" :: "v"(rq4), "v"(rq5), "v"(rq6), "v"(rq7));

  // Final-state values (state i -> lane i/7, slot i%7).
  int iN1 = N - 1, iN2 = N - 2;
  auto pick = [&](int sIdx) {
    float r = a0v;
    r = (sIdx == 1) ? a1v : r;
    r = (sIdx == 2) ? a2v : r;
    r = (sIdx == 3) ? a3v : r;
    r = (sIdx == 4) ? a4v : r;
    r = (sIdx == 5) ? a5v : r;
    r = (sIdx == 6) ? a6v : r;
    return r;
  };
  float vlast = __shfl(pick(iN1 % 7), iN1 / 7, 64);
  float vprev = __shfl(pick(iN2 % 7), iN2 / 7, 64);
  bool use_last = vlast > vprev;
  int pre = use_last ? iN1 : iN2;

  float al[4] = {0.f, 0.f, 0.f, 0.f};
  {
    int lbl = L - 1; int rr = lbl >> 6, ln = lbl & 63;
#pragma unroll
    for (int r = 0; r < 4; ++r)
      if (!use_last && rr == r && lane == ln) al[r] = (float)T;
  }

  // Backtrace from LDS offrow (rows of 64 u16; entry g of row t-1).
  const unsigned short* offrow = (const unsigned short*)smemf;
  int t = T - 1;
  int g = pre / 7, mm = pre - g * 7;
  while (t >= 1) {
    int K = (t < 7) ? t : 7;
    int pcur = g * 7 + mm;
    int gmax = g;
    unsigned short w0v = offrow[(size_t)(t - 1) * 64 + g];
    unsigned short cw[7][3];
    int gmn[7];
#pragma unroll
    for (int j = 1; j < 7; ++j) {
      if (j < K) {
        int lo = pcur - 2 * j; if (lo < 0) lo = 0;
        int gm = lo / 7;
        gmn[j] = gm;
#pragma unroll
        for (int r = 0; r < 3; ++r) {
          int gg = gm + r; if (gg > gmax) gg = gmax;
          cw[j][r] = offrow[(size_t)(t - 1 - j) * 64 + gg];
        }
      }
    }
#pragma unroll
    for (int j = 0; j < 7; ++j) {
      if (j < K) {
        unsigned w;
        if (j == 0) {
          w = w0v;
        } else {
          int gi = g - gmn[j];
          unsigned wva = cw[j][0], wvb = cw[j][1], wvc = cw[j][2];
          w = (gi == 0) ? wva : ((gi == 1) ? wvb : wvc);
        }
        unsigned off = (w >> (2 * mm)) & 3u;
        mm -= (int)off;
        bool bor = mm < 0;
        g = bor ? (g - 1) : g;
        mm = bor ? (mm + 7) : mm;
        int cur = g * 7 + mm;
        if (cur & 1) {
          int lbl = cur >> 1;
          int rr = lbl >> 6, ln = lbl & 63;
#pragma unroll
          for (int r = 0; r < 4; ++r)
            if (rr == r && lane == ln) al[r] = (float)(t - j);
        }
      }
    }
    t -= K;
  }

#pragma unroll
  for (int r = 0; r < 4; ++r) {
    int l = lane + 64 * r;
    if (l < L) ali[(size_t)b * L + l] = al[r];
  }
}

// ---------------------------------------------------------------------------
// Kernel C: one wave per (b,layer,o<L) row: dot(ali_out_row, pos) - ali,
// masked, squared; 4 rows/block -> per-block partial sum.
// ---------------------------------------------------------------------------
__global__ __launch_bounds__(256) void kC_rows(
    const float* __restrict__ ali_out, const float* __restrict__ ali,
    const int* __restrict__ ali_beg, float* __restrict__ partials,
    int B, int layers, int L, int T)
{
  __shared__ float ps[4];
  int wid = threadIdx.x >> 6, lane = threadIdx.x & 63;
  int row = blockIdx.x * 4 + wid;
  int nrows = B * layers * L;
  float val = 0.f;
  if (row < nrows) {
    int o = row % L;
    int bl = row / L;
    int layer = bl % layers;
    int b = bl / layers;
    const float* x = ali_out + ((size_t)(b * layers + layer) * (L + 1) + o) * T;
    float s = 0.f;
    if ((T & 3) == 0) {
      int nf4 = T >> 2;
      for (int k = lane; k < nf4; k += 64) {
        float4 v = reinterpret_cast<const float4*>(x)[k];
        float base = (float)(4 * k);
        s += v.x * (base + 1.f) + v.y * (base + 2.f) +
             v.z * (base + 3.f) + v.w * (base + 4.f);
      }
    } else {
      for (int k = lane; k < T; k += 64) s += x[k] * (float)(k + 1);
    }
    s = wave_sum_f(s);
    int cnt = 0;
    for (int l = lane; l < L; l += 64)
      cnt += (ali_beg[(size_t)b * L + l] != -1) ? 1 : 0;
    cnt = wave_sum_i(cnt);
    if (lane == 0) {
      float lat = (o >= cnt) ? 0.f : (s - ali[(size_t)b * L + o]);
      val = lat * lat;
    }
  }
  if (lane == 0) ps[wid] = val;
  __syncthreads();
  if (threadIdx.x == 0) partials[blockIdx.x] = ps[0] + ps[1] + ps[2] + ps[3];
}

// ---------------------------------------------------------------------------
// Kernel D: reduce partials, compute total = layers * sum(ylen), write scalar.
// ---------------------------------------------------------------------------
__global__ __launch_bounds__(256) void kD_final(
    const float* __restrict__ partials, int nparts,
    const int* __restrict__ ali_beg, int BL, int layers, int T,
    float* __restrict__ out)
{
  __shared__ float wred[4];
  __shared__ int wcnt[4];
  int tid = threadIdx.x, w = tid >> 6;
  float s = 0.f;
  for (int k = tid; k < nparts; k += 256) s += partials[k];
  s = wave_sum_f(s);
  int c = 0;
  for (int k = tid; k < BL; k += 256) c += (ali_beg[k] != -1) ? 1 : 0;
  c = wave_sum_i(c);
  if ((tid & 63) == 0) { wred[w] = s; wcnt[w] = c; }
  __syncthreads();
  if (tid == 0) {
    float ss = wred[0] + wred[1] + wred[2] + wred[3];
    float total = (float)(wcnt[0] + wcnt[1] + wcnt[2] + wcnt[3]) * (float)layers;
    out[0] = ss / total / (float)T;
  }
}

extern "C" void kernel_launch(void* const* d_in, const int* in_sizes, int n_in,
                              void* d_out, int out_size, void* d_ws, size_t ws_size,
                              hipStream_t stream)
{
  const float* ali_out   = (const float*)d_in[0];
  const int*   ali_beg   = (const int*)d_in[1];
  // d_in[2] ali_end, d_in[3] enc_mask, d_in[6] ctc_len: unused by reference math
  const float* ctc_out   = (const float*)d_in[4];
  const int*   ctc_label = (const int*)d_in[5];

  int B = in_sizes[6];
  int L = in_sizes[1] / B;
  int T = in_sizes[3] / B;
  int V = (int)((long long)in_sizes[4] / ((long long)B * T));
  int layers = (int)((long long)in_sizes[0] / ((long long)B * (L + 1) * T));

  int N = 2 * L + 1;
  int LANES = (N + 6) / 7;           // 58
  int ROWF = LANES * 4 + 8;          // 240 floats (960 B)
  int TPAD = T + 64;                 // ring over-read pad

  // workspace layout
  float* lp = (float*)d_ws;                              // B*TPAD*ROWF floats
  float* ali = lp + (size_t)B * TPAD * ROWF;             // B*L
  float* partials = ali + (size_t)B * L;                 // gridC
  int nrows = B * layers * L;
  int gridC = (nrows + 3) / 4;

  // A: logsumexp + gather into packed rows
  size_t shA = (size_t)V * sizeof(float);
  hipLaunchKernelGGL(kA_lse_gather, dim3(B * T), dim3(256), shA, stream,
                     ctc_out, ctc_label, lp, B, T, V, L, LANES, TPAD, ROWF);

  // B: Viterbi forward + backtrace (one wave per batch item)
  // LDS: offrow only, (T-1)*128 B
  size_t shB = (size_t)(T - 1) * 128;
  hipFuncSetAttribute(reinterpret_cast<const void*>(kB_viterbi),
                      hipFuncAttributeMaxDynamicSharedMemorySize, (int)shB);
  hipLaunchKernelGGL(kB_viterbi, dim3(B), dim3(64), shB, stream,
                     lp, ctc_label, ali, B, T, L, TPAD, ROWF);

  // C: expected-position rows + squared residual partials
  hipLaunchKernelGGL(kC_rows, dim3(gridC), dim3(256), 0, stream,
                     ali_out, ali, ali_beg, partials, B, layers, L, T);

  // D: finalize scalar
  hipLaunchKernelGGL(kD_final, dim3(1), dim3(256), 0, stream,
                     partials, gridC, ali_beg, B * L, layers, T, (float*)d_out);
}